// Round 2
// 137.861 us; speedup vs baseline: 1.0505x; 1.0505x over previous
//
#include <hip/hip_runtime.h>
#include <hip/hip_bf16.h>
#include <cstdint>

#define EPS 1e-5f
#define PATH_COEFF 0.04419417382415922f   // 1/sqrt(512)
#define CG110     0.5773502691896258f     // 1/sqrt(3)

typedef __bf16 v8bf __attribute__((ext_vector_type(8)));
typedef float  v4f  __attribute__((ext_vector_type(4)));
typedef _Float16 v4h __attribute__((ext_vector_type(4)));

static __device__ __forceinline__ unsigned short f2bf(float x){
    unsigned int u = __builtin_bit_cast(unsigned int, x);
    u += 0x7fffu + ((u >> 16) & 1u);      // RNE
    return (unsigned short)(u >> 16);
}
static __device__ __forceinline__ unsigned short f2h(float x){
    return __builtin_bit_cast(unsigned short, (_Float16)x);
}

// ---------------------------------------------------------------------------
// K0: fused prep. blocks [0,260): we_w2/we_b2 -> Vt2 frag-major (8KB LDS);
// [260,264): om_w1 -> w1t bf16 transpose; [264,776): per-row prep, wave/row.
// ---------------------------------------------------------------------------
__global__ __launch_bounds__(256)
void k_pre(const float* __restrict__ w2, const float* __restrict__ b2,
           unsigned short* __restrict__ Vt2,
           const float* __restrict__ om_w1, unsigned short* __restrict__ w1t,
           const float* __restrict__ x, const float* __restrict__ lng,
           const float* __restrict__ lnb, const float* __restrict__ we_w1,
           unsigned short* __restrict__ Q2, float* __restrict__ Ht, int N)
{
    __shared__ __align__(16) unsigned short tile[32][128];   // 8 KB
    int b = blockIdx.x;
    int t = threadIdx.x;

    if (b < 260){
        // ---- convV: Vt2[k][ps16][quad4][w128][8p] bf16 ----
        int k    = b >> 2;
        int slab = b & 3;
        const float* srcbase = (k < 64) ? (w2 + (size_t)k * 65536) : b2;
        for (int chunk = 0; chunk < 4; ++chunk){
            int pbase = slab*128 + chunk*32;
            #pragma unroll
            for (int i = 0; i < 4; ++i){
                int g = t + 256*i;
                int ploc = g >> 5, c4 = g & 31;
                const float4 v = *(const float4*)(srcbase + (size_t)(pbase + ploc)*128 + c4*4);
                unsigned int w0 = (unsigned)f2bf(v.x) | ((unsigned)f2bf(v.y) << 16);
                unsigned int w1 = (unsigned)f2bf(v.z) | ((unsigned)f2bf(v.w) << 16);
                *(uint2*)&tile[ploc][c4*4] = make_uint2(w0, w1);
            }
            __syncthreads();
            int w = t & 127, h = t >> 7;
            int ps = slab*4 + chunk;
            unsigned int words[8];
            #pragma unroll
            for (int g2 = 0; g2 < 8; ++g2)
                words[g2] = (unsigned)tile[h*16 + g2*2][w] | ((unsigned)tile[h*16 + g2*2 + 1][w] << 16);
            unsigned short* dq0 = Vt2 + (((size_t)(k*16 + ps)*4 + 2*h    )*128 + w)*8;
            unsigned short* dq1 = Vt2 + (((size_t)(k*16 + ps)*4 + 2*h + 1)*128 + w)*8;
            *(uint4*)dq0 = make_uint4(words[0], words[1], words[2], words[3]);
            *(uint4*)dq1 = make_uint4(words[4], words[5], words[6], words[7]);
            __syncthreads();
        }
    } else if (b < 264){
        // ---- convW: w1t[j512][w128] bf16 = om_w1[w][j] ----
        int j0 = (b - 260) * 128;
        for (int chunk = 0; chunk < 4; ++chunk){
            #pragma unroll
            for (int i = 0; i < 4; ++i){
                int g = t + 256*i;
                int wloc = g >> 5, c4 = g & 31;
                int w = chunk*32 + wloc;
                const float4 v = *(const float4*)(om_w1 + (size_t)w*512 + j0 + c4*4);
                unsigned int a = (unsigned)f2bf(v.x) | ((unsigned)f2bf(v.y) << 16);
                unsigned int bb = (unsigned)f2bf(v.z) | ((unsigned)f2bf(v.w) << 16);
                *(uint2*)&tile[wloc][c4*4] = make_uint2(a, bb);
            }
            __syncthreads();
            int jl = t & 127, h = t >> 7;
            unsigned int words[8];
            #pragma unroll
            for (int g2 = 0; g2 < 8; ++g2)
                words[g2] = (unsigned)tile[h*16 + g2*2][jl] | ((unsigned)tile[h*16 + g2*2 + 1][jl] << 16);
            unsigned short* dst = w1t + (size_t)(j0 + jl)*128 + chunk*32 + h*16;
            *(uint4*)dst       = make_uint4(words[0], words[1], words[2], words[3]);
            *(uint4*)(dst + 8) = make_uint4(words[4], words[5], words[6], words[7]);
            __syncthreads();
        }
    } else {
        // ---- prep: wave per row, 4 rows/block (R2 shape, no LDS) ----
        int wv = t >> 6, lane = t & 63;
        int row = (b - 264)*4 + wv;
        const float* xr = x + (size_t)row * 64;
        float f[16]; float mu = 0.f;
        #pragma unroll
        for (int u = 0; u < 16; ++u){ f[u] = xr[u]; mu += f[u]; }
        mu *= (1.f/16.f);
        float var = 0.f;
        #pragma unroll
        for (int u = 0; u < 16; ++u){ float d = f[u] - mu; var += d*d; }
        var *= (1.f/16.f);
        float inv = rsqrtf(var + EPS);
        float lnf[16];
        #pragma unroll
        for (int u = 0; u < 16; ++u) lnf[u] = (f[u]-mu)*inv*lng[u] + lnb[u];
        float h1 = 0.f;
        #pragma unroll
        for (int u = 0; u < 16; ++u) h1 += lnf[u] * we_w1[u*64 + lane];
        float h = h1 / (1.f + expf(-h1));
        Ht[(size_t)lane * N + row] = h;
        if (lane == 0) Ht[(size_t)64 * N + row] = 1.f;

        union { unsigned short qs[8]; uint4 v; } qu;
        #pragma unroll
        for (int j = 0; j < 8; ++j){
            int p = lane*8 + j;
            float q;
            if (p < 256){
                int u = p >> 4, v = p & 15;
                q = PATH_COEFF * f[u] * f[v];
            } else {
                int pp = p - 256;
                int u = pp >> 4, v = pp & 15;
                const float* ya = xr + 16 + u*3;
                const float* yb = xr + 16 + v*3;
                q = (PATH_COEFF * CG110) * (ya[0]*yb[0] + ya[1]*yb[1] + ya[2]*yb[2]);
            }
            qu.qs[j] = f2bf(q);
        }
        int rb = row >> 6, r64 = row & 63;
        int ps = lane >> 2, quad4 = lane & 3;
        *(uint4*)(Q2 + (((size_t)(rb*16 + ps)*4 + quad4)*64 + r64)*8) = qu.v;
    }
}

// ---------------------------------------------------------------------------
// K1: partial tile (fp16) = H[n,k] * sum_p Q[n,p] V[k,p,w]
// One k per block, 4 waves, 128x128 tile, lb(256,4). XCD swizzle: blockIdx =
// j*8+g, XCD g owns k in [8g,8g+8); k=64 rides g=0, j in [128,144).
// Partial layout is TILE-MAJOR: partial[mb][kb][128][128] so the reducer's
// 65 slices sit at 32KB stride in one contiguous 2MB region per mb.
// Epilogue: per-wave LDS transpose -> dense 128B row stores (no write amp).
// ---------------------------------------------------------------------------
__global__ __launch_bounds__(256, 4)
void k_main(const unsigned short* __restrict__ Q2, const unsigned short* __restrict__ Vt2,
            const float* __restrict__ Ht, unsigned short* __restrict__ partial, int N)
{
    __shared__ __align__(16) unsigned short stile[4][64*72];   // 36.9 KB
    int g = blockIdx.x & 7;
    int j = blockIdx.x >> 3;
    int kb, mb;
    if (j < 128){ mb = j >> 3; kb = g*8 + (j & 7); }
    else { if (g != 0) return; mb = j - 128; kb = 64; }

    int tid  = threadIdx.x;
    int lane = tid & 63, wv = tid >> 6;
    int r2 = wv >> 1, c2 = wv & 1;
    int quad = lane >> 4, l16 = lane & 15;
    int rowbase = mb*128 + r2*64;
    int rb = rowbase >> 6;
    int wbase = c2*64;

    const unsigned short* aroot = Q2  + (size_t)rb*32768 + quad*512  + l16*8;
    const unsigned short* broot = Vt2 + (size_t)kb*65536 + quad*1024 + (wbase + l16)*8;

    v4f acc[4][4];
    #pragma unroll
    for (int m=0;m<4;++m)
      #pragma unroll
      for (int n=0;n<4;++n)
        #pragma unroll
        for (int r=0;r<4;++r) acc[m][n][r] = 0.f;

    #pragma unroll 4
    for (int ps = 0; ps < 16; ++ps){
        const unsigned short* ap = aroot + ps*2048;
        const unsigned short* bp = broot + ps*4096;
        v8bf a[4], bb[4];
        #pragma unroll
        for (int m=0;m<4;++m) a[m]  = *(const v8bf*)(ap + m*128);
        #pragma unroll
        for (int n=0;n<4;++n) bb[n] = *(const v8bf*)(bp + n*128);
        #pragma unroll
        for (int m=0;m<4;++m)
          #pragma unroll
          for (int n=0;n<4;++n)
            acc[m][n] = __builtin_amdgcn_mfma_f32_16x16x32_bf16(a[m], bb[n], acc[m][n], 0, 0, 0);
    }

    // fold H and stage fp16 tile in wave-private LDS (no barrier needed)
    const float* hp = Ht + (size_t)kb*N + rowbase + quad*4;
    unsigned short* my = stile[wv];
    #pragma unroll
    for (int m=0;m<4;++m){
        v4f hv = *(const v4f*)(hp + m*16);
        #pragma unroll
        for (int n=0;n<4;++n)
          #pragma unroll
          for (int r=0;r<4;++r)
            my[(m*16 + quad*4 + r)*72 + n*16 + l16] = f2h(hv[r]*acc[m][n][r]);
    }
    // dense stores: 8 insts x (8 rows x 128B), tile-major destination
    unsigned short* gp = partial + ((size_t)(mb*65 + kb))*16384
                                 + (size_t)(r2*64)*128 + wbase;
    #pragma unroll
    for (int i = 0; i < 8; ++i){
        int row = i*8 + (lane >> 3);
        int c16 = (lane & 7)*8;
        uint4 v = *(const uint4*)&my[row*72 + c16];
        *(uint4*)(gp + (size_t)row*128 + c16) = v;
    }
}

// ---------------------------------------------------------------------------
// K2: reduce 65 fp16 slices + LayerNorm(128) -> lnf bf16.
// 256 blocks x 128 thr, 8 rows/block: thread owns (row = t>>4, w = (t&15)*8).
// 16B loads (v8 fp16) at 32KB slice stride (tile-major partial): one wave
// reads 1KB contiguous per slice step.
// ---------------------------------------------------------------------------
__global__ __launch_bounds__(128)
void k_red(const unsigned short* __restrict__ partial, const float* __restrict__ g,
           const float* __restrict__ b, unsigned short* __restrict__ lnf, int N)
{
    int t = threadIdx.x;
    int row = blockIdx.x * 8 + (t >> 4);
    int w8  = (t & 15) * 8;
    int mb  = row >> 7, rin = row & 127;

    const unsigned short* p0 = partial + (size_t)mb*65*16384 + (size_t)rin*128 + w8;

    float s[8];
    #pragma unroll
    for (int j = 0; j < 8; ++j) s[j] = 0.f;

    #pragma unroll 13
    for (int sl = 0; sl < 65; ++sl){
        uint4 raw = *(const uint4*)(p0 + (size_t)sl*16384);
        union { uint4 u; _Float16 h[8]; } cv; cv.u = raw;
        #pragma unroll
        for (int j = 0; j < 8; ++j) s[j] += (float)cv.h[j];
    }

    float sum = 0.f, sq = 0.f;
    #pragma unroll
    for (int j = 0; j < 8; ++j){ sum += s[j]; sq += s[j]*s[j]; }
    #pragma unroll
    for (int off = 8; off > 0; off >>= 1){
        sum += __shfl_xor(sum, off, 16);
        sq  += __shfl_xor(sq,  off, 16);
    }
    float mu  = sum * (1.f/128.f);
    float var = sq * (1.f/128.f) - mu*mu;
    float inv = rsqrtf(var + EPS);
    unsigned short o[8];
    #pragma unroll
    for (int j = 0; j < 8; ++j)
        o[j] = f2bf((s[j]-mu)*inv*g[w8+j] + b[w8+j]);
    *(uint4*)(lnf + (size_t)row*128 + w8) = *(uint4*)o;
}

// ---------------------------------------------------------------------------
// K3: out[n] = silu(lnf @ om_w1) @ om_w2 + om_b2. 64 blocks x 32 rows,
// 4 waves, wave wv owns j-range [wv*128, +128): 2x8 MFMA tiles. LDS reduce.
// ---------------------------------------------------------------------------
__global__ __launch_bounds__(256)
void k_mlp2(const unsigned short* __restrict__ lnf, const unsigned short* __restrict__ w1t,
            const float* __restrict__ w2, const float* __restrict__ b2,
            float* __restrict__ out, int N)
{
    __shared__ float red2[4][32];
    int tid = threadIdx.x, lane = tid & 63, wv = tid >> 6;
    int quad = lane >> 4, l16 = lane & 15;
    int rowbase = blockIdx.x * 32;
    int jbase = wv * 128;

    v4f acc[2][8];
    #pragma unroll
    for (int m=0;m<2;++m)
      #pragma unroll
      for (int n=0;n<8;++n)
        #pragma unroll
        for (int r=0;r<4;++r) acc[m][n][r] = 0.f;

    #pragma unroll
    for (int ps = 0; ps < 4; ++ps){
        v8bf a[2], bb[8];
        #pragma unroll
        for (int m=0;m<2;++m)
            a[m]  = *(const v8bf*)(lnf + (size_t)(rowbase + m*16 + l16)*128 + ps*32 + quad*8);
        #pragma unroll
        for (int n=0;n<8;++n)
            bb[n] = *(const v8bf*)(w1t + (size_t)(jbase + n*16 + l16)*128 + ps*32 + quad*8);
        #pragma unroll
        for (int m=0;m<2;++m)
          #pragma unroll
          for (int n=0;n<8;++n)
            acc[m][n] = __builtin_amdgcn_mfma_f32_16x16x32_bf16(a[m], bb[n], acc[m][n], 0, 0, 0);
    }

    float w2v[8];
    #pragma unroll
    for (int n=0;n<8;++n) w2v[n] = w2[jbase + n*16 + l16];

    #pragma unroll
    for (int m=0;m<2;++m){
        #pragma unroll
        for (int r=0;r<4;++r){
            float s = 0.f;
            #pragma unroll
            for (int n=0;n<8;++n){
                float v = acc[m][n][r];
                s += (v / (1.f + expf(-v))) * w2v[n];
            }
            #pragma unroll
            for (int off=8; off>0; off>>=1) s += __shfl_xor(s, off, 16);
            if (l16 == 0) red2[wv][m*16 + quad*4 + r] = s;
        }
    }
    __syncthreads();
    if (tid < 32)
        out[rowbase + tid] = red2[0][tid] + red2[1][tid] + red2[2][tid] + red2[3][tid] + b2[0];
}

// ---------------------------------------------------------------------------
extern "C" void kernel_launch(void* const* d_in, const int* in_sizes, int n_in,
                              void* d_out, int out_size, void* d_ws, size_t ws_size,
                              hipStream_t stream)
{
    const float* x     = (const float*)d_in[0];
    const float* we_g  = (const float*)d_in[1];
    const float* we_b  = (const float*)d_in[2];
    const float* we_w1 = (const float*)d_in[3];
    const float* we_w2 = (const float*)d_in[4];
    const float* we_b2 = (const float*)d_in[5];
    const float* om_g  = (const float*)d_in[6];
    const float* om_b  = (const float*)d_in[7];
    const float* om_w1 = (const float*)d_in[8];
    const float* om_w2 = (const float*)d_in[9];
    const float* om_b2 = (const float*)d_in[10];

    int N  = in_sizes[0] / 64;     // 2048

    char* ws = (char*)d_ws;
    size_t offV = 0;
    size_t szV  = (size_t)65*16*4*128*8*2;       // 8,519,680
    size_t offQ = offV + szV;
    size_t szQ  = (size_t)N*512*2;               // 2 MB
    size_t offH = offQ + szQ;
    size_t szH  = (size_t)65*N*4;
    size_t offP = offH + szH;
    size_t szP  = (size_t)65*N*128*2;            // 34 MB fp16
    size_t offL = offP + szP;
    size_t szL  = (size_t)N*128*2;
    size_t offW = offL + szL;                    // +128 KB

    unsigned short* Vt2 = (unsigned short*)(ws + offV);
    unsigned short* Q2  = (unsigned short*)(ws + offQ);
    float* Ht           = (float*)(ws + offH);
    unsigned short* Par = (unsigned short*)(ws + offP);
    unsigned short* Lnf = (unsigned short*)(ws + offL);
    unsigned short* W1t = (unsigned short*)(ws + offW);
    float* out = (float*)d_out;

    hipLaunchKernelGGL(k_pre,  dim3(264 + N/4), dim3(256), 0, stream,
                       we_w2, we_b2, Vt2, om_w1, W1t, x, we_g, we_b, we_w1, Q2, Ht, N);
    hipLaunchKernelGGL(k_main, dim3(144*8),     dim3(256), 0, stream, Q2, Vt2, Ht, Par, N);
    hipLaunchKernelGGL(k_red,  dim3(N/8),       dim3(128), 0, stream, Par, om_g, om_b, Lnf, N);
    hipLaunchKernelGGL(k_mlp2, dim3(N/32),      dim3(256), 0, stream, Lnf, W1t, om_w2, om_b2, out, N);
}

// Round 3
// 135.686 us; speedup vs baseline: 1.0673x; 1.0160x over previous
//
#include <hip/hip_runtime.h>
#include <hip/hip_bf16.h>
#include <cstdint>

#define EPS 1e-5f
#define PATH_COEFF 0.04419417382415922f   // 1/sqrt(512)
#define CG110     0.5773502691896258f     // 1/sqrt(3)

typedef __bf16 v8bf __attribute__((ext_vector_type(8)));
typedef float  v4f  __attribute__((ext_vector_type(4)));
typedef _Float16 v4h __attribute__((ext_vector_type(4)));

static __device__ __forceinline__ unsigned short f2bf(float x){
    unsigned int u = __builtin_bit_cast(unsigned int, x);
    u += 0x7fffu + ((u >> 16) & 1u);      // RNE
    return (unsigned short)(u >> 16);
}
static __device__ __forceinline__ unsigned short f2h(float x){
    return __builtin_bit_cast(unsigned short, (_Float16)x);
}

// ---------------------------------------------------------------------------
// K0: fused prep. blocks [0,260): we_w2/we_b2 -> Vt2 frag-major (8KB LDS);
// [260,264): om_w1 -> w1t bf16 transpose; [264,776): per-row prep, wave/row.
// ---------------------------------------------------------------------------
__global__ __launch_bounds__(256)
void k_pre(const float* __restrict__ w2, const float* __restrict__ b2,
           unsigned short* __restrict__ Vt2,
           const float* __restrict__ om_w1, unsigned short* __restrict__ w1t,
           const float* __restrict__ x, const float* __restrict__ lng,
           const float* __restrict__ lnb, const float* __restrict__ we_w1,
           unsigned short* __restrict__ Q2, float* __restrict__ Ht, int N)
{
    __shared__ __align__(16) unsigned short tile[32][128];   // 8 KB
    int b = blockIdx.x;
    int t = threadIdx.x;

    if (b < 260){
        // ---- convV: Vt2[k][ps16][quad4][w128][8p] bf16 ----
        int k    = b >> 2;
        int slab = b & 3;
        const float* srcbase = (k < 64) ? (w2 + (size_t)k * 65536) : b2;
        for (int chunk = 0; chunk < 4; ++chunk){
            int pbase = slab*128 + chunk*32;
            #pragma unroll
            for (int i = 0; i < 4; ++i){
                int g = t + 256*i;
                int ploc = g >> 5, c4 = g & 31;
                const float4 v = *(const float4*)(srcbase + (size_t)(pbase + ploc)*128 + c4*4);
                unsigned int w0 = (unsigned)f2bf(v.x) | ((unsigned)f2bf(v.y) << 16);
                unsigned int w1 = (unsigned)f2bf(v.z) | ((unsigned)f2bf(v.w) << 16);
                *(uint2*)&tile[ploc][c4*4] = make_uint2(w0, w1);
            }
            __syncthreads();
            int w = t & 127, h = t >> 7;
            int ps = slab*4 + chunk;
            unsigned int words[8];
            #pragma unroll
            for (int g2 = 0; g2 < 8; ++g2)
                words[g2] = (unsigned)tile[h*16 + g2*2][w] | ((unsigned)tile[h*16 + g2*2 + 1][w] << 16);
            unsigned short* dq0 = Vt2 + (((size_t)(k*16 + ps)*4 + 2*h    )*128 + w)*8;
            unsigned short* dq1 = Vt2 + (((size_t)(k*16 + ps)*4 + 2*h + 1)*128 + w)*8;
            *(uint4*)dq0 = make_uint4(words[0], words[1], words[2], words[3]);
            *(uint4*)dq1 = make_uint4(words[4], words[5], words[6], words[7]);
            __syncthreads();
        }
    } else if (b < 264){
        // ---- convW: w1t[j512][w128] bf16 = om_w1[w][j] ----
        int j0 = (b - 260) * 128;
        for (int chunk = 0; chunk < 4; ++chunk){
            #pragma unroll
            for (int i = 0; i < 4; ++i){
                int g = t + 256*i;
                int wloc = g >> 5, c4 = g & 31;
                int w = chunk*32 + wloc;
                const float4 v = *(const float4*)(om_w1 + (size_t)w*512 + j0 + c4*4);
                unsigned int a = (unsigned)f2bf(v.x) | ((unsigned)f2bf(v.y) << 16);
                unsigned int bb = (unsigned)f2bf(v.z) | ((unsigned)f2bf(v.w) << 16);
                *(uint2*)&tile[wloc][c4*4] = make_uint2(a, bb);
            }
            __syncthreads();
            int jl = t & 127, h = t >> 7;
            unsigned int words[8];
            #pragma unroll
            for (int g2 = 0; g2 < 8; ++g2)
                words[g2] = (unsigned)tile[h*16 + g2*2][jl] | ((unsigned)tile[h*16 + g2*2 + 1][jl] << 16);
            unsigned short* dst = w1t + (size_t)(j0 + jl)*128 + chunk*32 + h*16;
            *(uint4*)dst       = make_uint4(words[0], words[1], words[2], words[3]);
            *(uint4*)(dst + 8) = make_uint4(words[4], words[5], words[6], words[7]);
            __syncthreads();
        }
    } else {
        // ---- prep: wave per row, 4 rows/block (R2 shape, no LDS) ----
        int wv = t >> 6, lane = t & 63;
        int row = (b - 264)*4 + wv;
        const float* xr = x + (size_t)row * 64;
        float f[16]; float mu = 0.f;
        #pragma unroll
        for (int u = 0; u < 16; ++u){ f[u] = xr[u]; mu += f[u]; }
        mu *= (1.f/16.f);
        float var = 0.f;
        #pragma unroll
        for (int u = 0; u < 16; ++u){ float d = f[u] - mu; var += d*d; }
        var *= (1.f/16.f);
        float inv = rsqrtf(var + EPS);
        float lnf[16];
        #pragma unroll
        for (int u = 0; u < 16; ++u) lnf[u] = (f[u]-mu)*inv*lng[u] + lnb[u];
        float h1 = 0.f;
        #pragma unroll
        for (int u = 0; u < 16; ++u) h1 += lnf[u] * we_w1[u*64 + lane];
        float h = h1 / (1.f + expf(-h1));
        Ht[(size_t)lane * N + row] = h;
        if (lane == 0) Ht[(size_t)64 * N + row] = 1.f;

        union { unsigned short qs[8]; uint4 v; } qu;
        #pragma unroll
        for (int j = 0; j < 8; ++j){
            int p = lane*8 + j;
            float q;
            if (p < 256){
                int u = p >> 4, v = p & 15;
                q = PATH_COEFF * f[u] * f[v];
            } else {
                int pp = p - 256;
                int u = pp >> 4, v = pp & 15;
                const float* ya = xr + 16 + u*3;
                const float* yb = xr + 16 + v*3;
                q = (PATH_COEFF * CG110) * (ya[0]*yb[0] + ya[1]*yb[1] + ya[2]*yb[2]);
            }
            qu.qs[j] = f2bf(q);
        }
        int rb = row >> 6, r64 = row & 63;
        int ps = lane >> 2, quad4 = lane & 3;
        *(uint4*)(Q2 + (((size_t)(rb*16 + ps)*4 + quad4)*64 + r64)*8) = qu.v;
    }
}

// ---------------------------------------------------------------------------
// K1 (Kg=2): each block owns kg = pair of k slices {2kg, 2kg+1} (kg=32 -> k=64
// alone, masked via sel). A (Q) fragments loaded ONCE per ps and reused for
// both k's -> A-side L2 traffic halves. Two acc sets; H-fold in epilogue:
// res = h0*accA + sel*h1*accB. Partial = [mb][33][128][128] fp16.
// XCD swizzle: blockIdx = j*8+g; XCD g owns kg in [4g,4g+4) (k in [8g,8g+8)).
// kg=32 rides g=0, j in [64,80). lb(256,2): ~200 VGPR, 2 blocks/CU.
// ---------------------------------------------------------------------------
__global__ __launch_bounds__(256, 2)
void k_main(const unsigned short* __restrict__ Q2, const unsigned short* __restrict__ Vt2,
            const float* __restrict__ Ht, unsigned short* __restrict__ partial, int N)
{
    __shared__ __align__(16) unsigned short stile[4][64*72];   // 36.9 KB
    int g = blockIdx.x & 7;
    int j = blockIdx.x >> 3;
    int kg, mb;
    if (j < 64){ mb = j >> 2; kg = g*4 + (j & 3); }
    else { if (g != 0) return; mb = j - 64; kg = 32; }

    int tid  = threadIdx.x;
    int lane = tid & 63, wv = tid >> 6;
    int r2 = wv >> 1, c2 = wv & 1;
    int quad = lane >> 4, l16 = lane & 15;
    int rowbase = mb*128 + r2*64;
    int rb = rowbase >> 6;
    int wbase = c2*64;

    int k0 = kg*2;                       // kg=32 -> k0=64
    int k1 = (kg == 32) ? 64 : k0 + 1;
    float sel = (kg == 32) ? 0.f : 1.f;

    const unsigned short* aroot  = Q2  + (size_t)rb*32768 + quad*512  + l16*8;
    const unsigned short* broot0 = Vt2 + (size_t)k0*65536 + quad*1024 + (wbase + l16)*8;
    const unsigned short* broot1 = Vt2 + (size_t)k1*65536 + quad*1024 + (wbase + l16)*8;

    v4f accA[4][4], accB[4][4];
    #pragma unroll
    for (int m=0;m<4;++m)
      #pragma unroll
      for (int n=0;n<4;++n)
        #pragma unroll
        for (int r=0;r<4;++r){ accA[m][n][r] = 0.f; accB[m][n][r] = 0.f; }

    #pragma unroll 2
    for (int ps = 0; ps < 16; ++ps){
        const unsigned short* ap  = aroot  + ps*2048;
        const unsigned short* bp0 = broot0 + ps*4096;
        const unsigned short* bp1 = broot1 + ps*4096;
        v8bf a[4], b0[4], b1[4];
        #pragma unroll
        for (int m=0;m<4;++m) a[m]  = *(const v8bf*)(ap  + m*128);
        #pragma unroll
        for (int n=0;n<4;++n) b0[n] = *(const v8bf*)(bp0 + n*128);
        #pragma unroll
        for (int n=0;n<4;++n) b1[n] = *(const v8bf*)(bp1 + n*128);
        #pragma unroll
        for (int m=0;m<4;++m)
          #pragma unroll
          for (int n=0;n<4;++n)
            accA[m][n] = __builtin_amdgcn_mfma_f32_16x16x32_bf16(a[m], b0[n], accA[m][n], 0, 0, 0);
        #pragma unroll
        for (int m=0;m<4;++m)
          #pragma unroll
          for (int n=0;n<4;++n)
            accB[m][n] = __builtin_amdgcn_mfma_f32_16x16x32_bf16(a[m], b1[n], accB[m][n], 0, 0, 0);
    }

    // H-fold both k's, stage fp16 tile in wave-private LDS (no barrier needed)
    const float* hp0 = Ht + (size_t)k0*N + rowbase + quad*4;
    const float* hp1 = Ht + (size_t)k1*N + rowbase + quad*4;
    unsigned short* my = stile[wv];
    #pragma unroll
    for (int m=0;m<4;++m){
        v4f h0 = *(const v4f*)(hp0 + m*16);
        v4f h1 = *(const v4f*)(hp1 + m*16);
        #pragma unroll
        for (int n=0;n<4;++n)
          #pragma unroll
          for (int r=0;r<4;++r)
            my[(m*16 + quad*4 + r)*72 + n*16 + l16] =
                f2h(h0[r]*accA[m][n][r] + sel*h1[r]*accB[m][n][r]);
    }
    // dense stores: 8 insts x (8 rows x 128B), tile-major destination
    unsigned short* gp = partial + ((size_t)(mb*33 + kg))*16384
                                 + (size_t)(r2*64)*128 + wbase;
    #pragma unroll
    for (int i = 0; i < 8; ++i){
        int row = i*8 + (lane >> 3);
        int c16 = (lane & 7)*8;
        uint4 v = *(const uint4*)&my[row*72 + c16];
        *(uint4*)(gp + (size_t)row*128 + c16) = v;
    }
}

// ---------------------------------------------------------------------------
// K2: reduce 33 fp16 slices + LayerNorm(128) -> lnf bf16.
// 256 blocks x 128 thr, 8 rows/block: thread owns (row = t>>4, w = (t&15)*8).
// 16B loads at 32KB slice stride within a contiguous 1.06MB region per mb.
// ---------------------------------------------------------------------------
__global__ __launch_bounds__(128)
void k_red(const unsigned short* __restrict__ partial, const float* __restrict__ g,
           const float* __restrict__ b, unsigned short* __restrict__ lnf, int N)
{
    int t = threadIdx.x;
    int row = blockIdx.x * 8 + (t >> 4);
    int w8  = (t & 15) * 8;
    int mb  = row >> 7, rin = row & 127;

    const unsigned short* p0 = partial + (size_t)mb*33*16384 + (size_t)rin*128 + w8;

    float s[8];
    #pragma unroll
    for (int j = 0; j < 8; ++j) s[j] = 0.f;

    #pragma unroll 11
    for (int sl = 0; sl < 33; ++sl){
        uint4 raw = *(const uint4*)(p0 + (size_t)sl*16384);
        union { uint4 u; _Float16 h[8]; } cv; cv.u = raw;
        #pragma unroll
        for (int j = 0; j < 8; ++j) s[j] += (float)cv.h[j];
    }

    float sum = 0.f, sq = 0.f;
    #pragma unroll
    for (int j = 0; j < 8; ++j){ sum += s[j]; sq += s[j]*s[j]; }
    #pragma unroll
    for (int off = 8; off > 0; off >>= 1){
        sum += __shfl_xor(sum, off, 16);
        sq  += __shfl_xor(sq,  off, 16);
    }
    float mu  = sum * (1.f/128.f);
    float var = sq * (1.f/128.f) - mu*mu;
    float inv = rsqrtf(var + EPS);
    unsigned short o[8];
    #pragma unroll
    for (int j = 0; j < 8; ++j)
        o[j] = f2bf((s[j]-mu)*inv*g[w8+j] + b[w8+j]);
    *(uint4*)(lnf + (size_t)row*128 + w8) = *(uint4*)o;
}

// ---------------------------------------------------------------------------
// K3: out[n] = silu(lnf @ om_w1) @ om_w2 + om_b2. 64 blocks x 32 rows,
// 4 waves, wave wv owns j-range [wv*128, +128): 2x8 MFMA tiles. LDS reduce.
// ---------------------------------------------------------------------------
__global__ __launch_bounds__(256)
void k_mlp2(const unsigned short* __restrict__ lnf, const unsigned short* __restrict__ w1t,
            const float* __restrict__ w2, const float* __restrict__ b2,
            float* __restrict__ out, int N)
{
    __shared__ float red2[4][32];
    int tid = threadIdx.x, lane = tid & 63, wv = tid >> 6;
    int quad = lane >> 4, l16 = lane & 15;
    int rowbase = blockIdx.x * 32;
    int jbase = wv * 128;

    v4f acc[2][8];
    #pragma unroll
    for (int m=0;m<2;++m)
      #pragma unroll
      for (int n=0;n<8;++n)
        #pragma unroll
        for (int r=0;r<4;++r) acc[m][n][r] = 0.f;

    #pragma unroll
    for (int ps = 0; ps < 4; ++ps){
        v8bf a[2], bb[8];
        #pragma unroll
        for (int m=0;m<2;++m)
            a[m]  = *(const v8bf*)(lnf + (size_t)(rowbase + m*16 + l16)*128 + ps*32 + quad*8);
        #pragma unroll
        for (int n=0;n<8;++n)
            bb[n] = *(const v8bf*)(w1t + (size_t)(jbase + n*16 + l16)*128 + ps*32 + quad*8);
        #pragma unroll
        for (int m=0;m<2;++m)
          #pragma unroll
          for (int n=0;n<8;++n)
            acc[m][n] = __builtin_amdgcn_mfma_f32_16x16x32_bf16(a[m], bb[n], acc[m][n], 0, 0, 0);
    }

    float w2v[8];
    #pragma unroll
    for (int n=0;n<8;++n) w2v[n] = w2[jbase + n*16 + l16];

    #pragma unroll
    for (int m=0;m<2;++m){
        #pragma unroll
        for (int r=0;r<4;++r){
            float s = 0.f;
            #pragma unroll
            for (int n=0;n<8;++n){
                float v = acc[m][n][r];
                s += (v / (1.f + expf(-v))) * w2v[n];
            }
            #pragma unroll
            for (int off=8; off>0; off>>=1) s += __shfl_xor(s, off, 16);
            if (l16 == 0) red2[wv][m*16 + quad*4 + r] = s;
        }
    }
    __syncthreads();
    if (tid < 32)
        out[rowbase + tid] = red2[0][tid] + red2[1][tid] + red2[2][tid] + red2[3][tid] + b2[0];
}

// ---------------------------------------------------------------------------
extern "C" void kernel_launch(void* const* d_in, const int* in_sizes, int n_in,
                              void* d_out, int out_size, void* d_ws, size_t ws_size,
                              hipStream_t stream)
{
    const float* x     = (const float*)d_in[0];
    const float* we_g  = (const float*)d_in[1];
    const float* we_b  = (const float*)d_in[2];
    const float* we_w1 = (const float*)d_in[3];
    const float* we_w2 = (const float*)d_in[4];
    const float* we_b2 = (const float*)d_in[5];
    const float* om_g  = (const float*)d_in[6];
    const float* om_b  = (const float*)d_in[7];
    const float* om_w1 = (const float*)d_in[8];
    const float* om_w2 = (const float*)d_in[9];
    const float* om_b2 = (const float*)d_in[10];

    int N  = in_sizes[0] / 64;     // 2048

    char* ws = (char*)d_ws;
    size_t offV = 0;
    size_t szV  = (size_t)65*16*4*128*8*2;       // 8,519,680
    size_t offQ = offV + szV;
    size_t szQ  = (size_t)N*512*2;               // 2 MB
    size_t offH = offQ + szQ;
    size_t szH  = (size_t)65*N*4;
    size_t offP = offH + szH;
    size_t szP  = (size_t)(N/128)*33*16384*2;    // 17.3 MB fp16
    size_t offL = offP + szP;
    size_t szL  = (size_t)N*128*2;
    size_t offW = offL + szL;                    // +128 KB

    unsigned short* Vt2 = (unsigned short*)(ws + offV);
    unsigned short* Q2  = (unsigned short*)(ws + offQ);
    float* Ht           = (float*)(ws + offH);
    unsigned short* Par = (unsigned short*)(ws + offP);
    unsigned short* Lnf = (unsigned short*)(ws + offL);
    unsigned short* W1t = (unsigned short*)(ws + offW);
    float* out = (float*)d_out;

    hipLaunchKernelGGL(k_pre,  dim3(264 + N/4), dim3(256), 0, stream,
                       we_w2, we_b2, Vt2, om_w1, W1t, x, we_g, we_b, we_w1, Q2, Ht, N);
    hipLaunchKernelGGL(k_main, dim3(80*8),      dim3(256), 0, stream, Q2, Vt2, Ht, Par, N);
    hipLaunchKernelGGL(k_red,  dim3(N/8),       dim3(128), 0, stream, Par, om_g, om_b, Lnf, N);
    hipLaunchKernelGGL(k_mlp2, dim3(N/32),      dim3(256), 0, stream, Lnf, W1t, om_w2, om_b2, out, N);
}

// Round 5
// 134.981 us; speedup vs baseline: 1.0729x; 1.0052x over previous
//
#include <hip/hip_runtime.h>
#include <hip/hip_bf16.h>
#include <cstdint>

#define EPS 1e-5f
#define PATH_COEFF 0.04419417382415922f   // 1/sqrt(512)
#define CG110     0.5773502691896258f     // 1/sqrt(3)

typedef __bf16 v8bf __attribute__((ext_vector_type(8)));
typedef float  v4f  __attribute__((ext_vector_type(4)));
typedef _Float16 v4h __attribute__((ext_vector_type(4)));

static __device__ __forceinline__ unsigned short f2bf(float x){
    unsigned int u = __builtin_bit_cast(unsigned int, x);
    u += 0x7fffu + ((u >> 16) & 1u);      // RNE
    return (unsigned short)(u >> 16);
}
static __device__ __forceinline__ unsigned short f2h(float x){
    return __builtin_bit_cast(unsigned short, (_Float16)x);
}

// ---------------------------------------------------------------------------
// K0: fused prep. blocks [0,260): we_w2/we_b2 -> Vt2 frag-major (8KB LDS);
// [260,264): om_w1 -> w1t bf16 transpose; [264,776): per-row prep, wave/row,
// with LDS-transposed Q2/Ht stores (full 64B sectors, no write amplification).
// ---------------------------------------------------------------------------
__global__ __launch_bounds__(256)
void k_pre(const float* __restrict__ w2, const float* __restrict__ b2,
           unsigned short* __restrict__ Vt2,
           const float* __restrict__ om_w1, unsigned short* __restrict__ w1t,
           const float* __restrict__ x, const float* __restrict__ lng,
           const float* __restrict__ lnb, const float* __restrict__ we_w1,
           unsigned short* __restrict__ Q2, float* __restrict__ Ht, int N)
{
    __shared__ __align__(16) unsigned short tile[32][128];   // 8 KB
    __shared__ __align__(16) uint4 qtile[64][4];             // 4 KB
    __shared__ float htile[4][65];                           // 1.04 KB
    int b = blockIdx.x;
    int t = threadIdx.x;

    if (b < 260){
        // ---- convV: Vt2[k][ps16][quad4][w128][8p] bf16 ----
        int k    = b >> 2;
        int slab = b & 3;
        const float* srcbase = (k < 64) ? (w2 + (size_t)k * 65536) : b2;
        for (int chunk = 0; chunk < 4; ++chunk){
            int pbase = slab*128 + chunk*32;
            #pragma unroll
            for (int i = 0; i < 4; ++i){
                int g = t + 256*i;
                int ploc = g >> 5, c4 = g & 31;
                const float4 v = *(const float4*)(srcbase + (size_t)(pbase + ploc)*128 + c4*4);
                unsigned int w0 = (unsigned)f2bf(v.x) | ((unsigned)f2bf(v.y) << 16);
                unsigned int w1 = (unsigned)f2bf(v.z) | ((unsigned)f2bf(v.w) << 16);
                *(uint2*)&tile[ploc][c4*4] = make_uint2(w0, w1);
            }
            __syncthreads();
            int w = t & 127, h = t >> 7;
            int ps = slab*4 + chunk;
            unsigned int words[8];
            #pragma unroll
            for (int g2 = 0; g2 < 8; ++g2)
                words[g2] = (unsigned)tile[h*16 + g2*2][w] | ((unsigned)tile[h*16 + g2*2 + 1][w] << 16);
            unsigned short* dq0 = Vt2 + (((size_t)(k*16 + ps)*4 + 2*h    )*128 + w)*8;
            unsigned short* dq1 = Vt2 + (((size_t)(k*16 + ps)*4 + 2*h + 1)*128 + w)*8;
            *(uint4*)dq0 = make_uint4(words[0], words[1], words[2], words[3]);
            *(uint4*)dq1 = make_uint4(words[4], words[5], words[6], words[7]);
            __syncthreads();
        }
    } else if (b < 264){
        // ---- convW: w1t[j512][w128] bf16 = om_w1[w][j] ----
        int j0 = (b - 260) * 128;
        for (int chunk = 0; chunk < 4; ++chunk){
            #pragma unroll
            for (int i = 0; i < 4; ++i){
                int g = t + 256*i;
                int wloc = g >> 5, c4 = g & 31;
                int w = chunk*32 + wloc;
                const float4 v = *(const float4*)(om_w1 + (size_t)w*512 + j0 + c4*4);
                unsigned int a = (unsigned)f2bf(v.x) | ((unsigned)f2bf(v.y) << 16);
                unsigned int bb = (unsigned)f2bf(v.z) | ((unsigned)f2bf(v.w) << 16);
                *(uint2*)&tile[wloc][c4*4] = make_uint2(a, bb);
            }
            __syncthreads();
            int jl = t & 127, h = t >> 7;
            unsigned int words[8];
            #pragma unroll
            for (int g2 = 0; g2 < 8; ++g2)
                words[g2] = (unsigned)tile[h*16 + g2*2][jl] | ((unsigned)tile[h*16 + g2*2 + 1][jl] << 16);
            unsigned short* dst = w1t + (size_t)(j0 + jl)*128 + chunk*32 + h*16;
            *(uint4*)dst       = make_uint4(words[0], words[1], words[2], words[3]);
            *(uint4*)(dst + 8) = make_uint4(words[4], words[5], words[6], words[7]);
            __syncthreads();
        }
    } else {
        // ---- prep: wave per row, 4 rows/block; LDS transpose -> dense stores
        int wv = t >> 6, lane = t & 63;
        int row0 = (b - 264)*4;
        int row  = row0 + wv;
        const float* xr = x + (size_t)row * 64;
        float f[16]; float mu = 0.f;
        #pragma unroll
        for (int u = 0; u < 16; ++u){ f[u] = xr[u]; mu += f[u]; }
        mu *= (1.f/16.f);
        float var = 0.f;
        #pragma unroll
        for (int u = 0; u < 16; ++u){ float d = f[u] - mu; var += d*d; }
        var *= (1.f/16.f);
        float inv = rsqrtf(var + EPS);
        float lnf[16];
        #pragma unroll
        for (int u = 0; u < 16; ++u) lnf[u] = (f[u]-mu)*inv*lng[u] + lnb[u];
        float h1 = 0.f;
        #pragma unroll
        for (int u = 0; u < 16; ++u) h1 += lnf[u] * we_w1[u*64 + lane];
        float h = h1 / (1.f + expf(-h1));
        htile[wv][lane] = h;
        if (lane == 0) htile[wv][64] = 1.f;

        union { unsigned short qs[8]; uint4 v; } qu;
        #pragma unroll
        for (int j = 0; j < 8; ++j){
            int p = lane*8 + j;
            float q;
            if (p < 256){
                int u = p >> 4, v = p & 15;
                q = PATH_COEFF * f[u] * f[v];
            } else {
                int pp = p - 256;
                int u = pp >> 4, v = pp & 15;
                const float* ya = xr + 16 + u*3;
                const float* yb = xr + 16 + v*3;
                q = (PATH_COEFF * CG110) * (ya[0]*yb[0] + ya[1]*yb[1] + ya[2]*yb[2]);
            }
            qu.qs[j] = f2bf(q);
        }
        // slot = (ps*4 + quad4) == lane; stage per-row, then thread t emits
        // slot (t>>2), row (t&3): 4 consecutive threads = 64B dense sector.
        qtile[lane][wv] = qu.v;
        __syncthreads();

        int rb = row0 >> 6, r64base = row0 & 63;
        {
            int slot = t >> 2, rr = t & 3;
            // Q2 uint4 layout: [rb][slot64][r64]: idx = rb*4096 + slot*64 + r64
            ((uint4*)Q2)[(size_t)rb*4096 + (size_t)slot*64 + r64base + rr] = qtile[slot][rr];
        }
        if (t < 65){
            float4 hv = make_float4(htile[0][t], htile[1][t], htile[2][t], htile[3][t]);
            *(float4*)(Ht + (size_t)t*N + row0) = hv;
        }
    }
}

// ---------------------------------------------------------------------------
// K1 (Kg=2): each block owns kg = pair of k slices {2kg, 2kg+1} (kg=32 -> k=64
// alone, masked via sel). A (Q) fragments loaded ONCE per ps and reused for
// both k's. Two acc sets; H-fold in epilogue. Partial = [mb][33][128][128] fp16.
// XCD swizzle: blockIdx = j*8+g; XCD g owns kg in [4g,4g+4). kg=32 rides g=0.
// ---------------------------------------------------------------------------
__global__ __launch_bounds__(256, 2)
void k_main(const unsigned short* __restrict__ Q2, const unsigned short* __restrict__ Vt2,
            const float* __restrict__ Ht, unsigned short* __restrict__ partial, int N)
{
    __shared__ __align__(16) unsigned short stile[4][64*72];   // 36.9 KB
    int g = blockIdx.x & 7;
    int j = blockIdx.x >> 3;
    int kg, mb;
    if (j < 64){ mb = j >> 2; kg = g*4 + (j & 3); }
    else { if (g != 0) return; mb = j - 64; kg = 32; }

    int tid  = threadIdx.x;
    int lane = tid & 63, wv = tid >> 6;
    int r2 = wv >> 1, c2 = wv & 1;
    int quad = lane >> 4, l16 = lane & 15;
    int rowbase = mb*128 + r2*64;
    int rb = rowbase >> 6;
    int wbase = c2*64;

    int k0 = kg*2;                       // kg=32 -> k0=64
    int k1 = (kg == 32) ? 64 : k0 + 1;
    float sel = (kg == 32) ? 0.f : 1.f;

    const unsigned short* aroot  = Q2  + (size_t)rb*32768 + quad*512  + l16*8;
    const unsigned short* broot0 = Vt2 + (size_t)k0*65536 + quad*1024 + (wbase + l16)*8;
    const unsigned short* broot1 = Vt2 + (size_t)k1*65536 + quad*1024 + (wbase + l16)*8;

    v4f accA[4][4], accB[4][4];
    #pragma unroll
    for (int m=0;m<4;++m)
      #pragma unroll
      for (int n=0;n<4;++n)
        #pragma unroll
        for (int r=0;r<4;++r){ accA[m][n][r] = 0.f; accB[m][n][r] = 0.f; }

    #pragma unroll 2
    for (int ps = 0; ps < 16; ++ps){
        const unsigned short* ap  = aroot  + ps*2048;
        const unsigned short* bp0 = broot0 + ps*4096;
        const unsigned short* bp1 = broot1 + ps*4096;
        v8bf a[4], b0[4], b1[4];
        #pragma unroll
        for (int m=0;m<4;++m) a[m]  = *(const v8bf*)(ap  + m*128);
        #pragma unroll
        for (int n=0;n<4;++n) b0[n] = *(const v8bf*)(bp0 + n*128);
        #pragma unroll
        for (int n=0;n<4;++n) b1[n] = *(const v8bf*)(bp1 + n*128);
        #pragma unroll
        for (int m=0;m<4;++m)
          #pragma unroll
          for (int n=0;n<4;++n)
            accA[m][n] = __builtin_amdgcn_mfma_f32_16x16x32_bf16(a[m], b0[n], accA[m][n], 0, 0, 0);
        #pragma unroll
        for (int m=0;m<4;++m)
          #pragma unroll
          for (int n=0;n<4;++n)
            accB[m][n] = __builtin_amdgcn_mfma_f32_16x16x32_bf16(a[m], b1[n], accB[m][n], 0, 0, 0);
    }

    // H-fold both k's, stage fp16 tile in wave-private LDS (no barrier needed)
    const float* hp0 = Ht + (size_t)k0*N + rowbase + quad*4;
    const float* hp1 = Ht + (size_t)k1*N + rowbase + quad*4;
    unsigned short* my = stile[wv];
    #pragma unroll
    for (int m=0;m<4;++m){
        v4f h0 = *(const v4f*)(hp0 + m*16);
        v4f h1 = *(const v4f*)(hp1 + m*16);
        #pragma unroll
        for (int n=0;n<4;++n)
          #pragma unroll
          for (int r=0;r<4;++r)
            my[(m*16 + quad*4 + r)*72 + n*16 + l16] =
                f2h(h0[r]*accA[m][n][r] + sel*h1[r]*accB[m][n][r]);
    }
    // dense stores: 8 insts x (8 rows x 128B), tile-major destination
    unsigned short* gp = partial + ((size_t)(mb*33 + kg))*16384
                                 + (size_t)(r2*64)*128 + wbase;
    #pragma unroll
    for (int i = 0; i < 8; ++i){
        int row = i*8 + (lane >> 3);
        int c16 = (lane & 7)*8;
        uint4 v = *(const uint4*)&my[row*72 + c16];
        *(uint4*)(gp + (size_t)row*128 + c16) = v;
    }
}

// ---------------------------------------------------------------------------
// K2 (fused tail): reduce 33 fp16 slices + LayerNorm -> LDS bf16, then
// out[n] = silu(lnf @ om_w1) @ om_w2 + om_b2, all in one kernel.
// 128 blocks x 128 thr, 16 rows/block. Phase 1: thread owns (row, w8) twice
// (halves), 16B loads at 32KB stride; LN shuffle width 16. Phase 2: 2 waves,
// wave wv owns j-range [wv*256,+256): acc[16], A from LDS, B from w1t.
// ---------------------------------------------------------------------------
__global__ __launch_bounds__(128)
void k_tail(const unsigned short* __restrict__ partial, const float* __restrict__ g,
            const float* __restrict__ b, const unsigned short* __restrict__ w1t,
            const float* __restrict__ w2, const float* __restrict__ b2,
            float* __restrict__ out, int N)
{
    __shared__ __align__(16) unsigned short lnf_lds[16][128];   // 4 KB
    __shared__ float red2[2][16];
    int t = threadIdx.x;
    int rowbase = blockIdx.x * 16;
    int mb = rowbase >> 7;
    const unsigned short* pbase = partial + (size_t)mb*33*16384;

    // ---- phase 1: reduce + LN, two row-halves sequentially ----
    #pragma unroll
    for (int half = 0; half < 2; ++half){
        int rl  = half*8 + (t >> 4);           // 0..15
        int w8  = (t & 15) * 8;
        int row = rowbase + rl;
        int rin = row & 127;
        const unsigned short* p0 = pbase + (size_t)rin*128 + w8;

        float s[8];
        #pragma unroll
        for (int j2 = 0; j2 < 8; ++j2) s[j2] = 0.f;
        #pragma unroll 11
        for (int sl = 0; sl < 33; ++sl){
            uint4 raw = *(const uint4*)(p0 + (size_t)sl*16384);
            union { uint4 u; _Float16 h[8]; } cv; cv.u = raw;
            #pragma unroll
            for (int j2 = 0; j2 < 8; ++j2) s[j2] += (float)cv.h[j2];
        }
        float sum = 0.f, sq = 0.f;
        #pragma unroll
        for (int j2 = 0; j2 < 8; ++j2){ sum += s[j2]; sq += s[j2]*s[j2]; }
        #pragma unroll
        for (int off = 8; off > 0; off >>= 1){
            sum += __shfl_xor(sum, off, 16);
            sq  += __shfl_xor(sq,  off, 16);
        }
        float mu  = sum * (1.f/128.f);
        float var = sq * (1.f/128.f) - mu*mu;
        float inv = rsqrtf(var + EPS);
        unsigned short o[8];
        #pragma unroll
        for (int j2 = 0; j2 < 8; ++j2)
            o[j2] = f2bf((s[j2]-mu)*inv*g[w8+j2] + b[w8+j2]);
        *(uint4*)&lnf_lds[rl][w8] = *(uint4*)o;
    }
    __syncthreads();

    // ---- phase 2: silu(lnf @ om_w1) @ om_w2 ----
    int lane = t & 63, wv = t >> 6;
    int quad = lane >> 4, l16 = lane & 15;
    int jbase = wv * 256;

    v4f acc[16];
    #pragma unroll
    for (int n=0;n<16;++n)
      #pragma unroll
      for (int r=0;r<4;++r) acc[n][r] = 0.f;

    #pragma unroll
    for (int ps = 0; ps < 4; ++ps){
        v8bf a = *(const v8bf*)&lnf_lds[l16][ps*32 + quad*8];
        v8bf bb[16];
        #pragma unroll
        for (int n=0;n<16;++n)
            bb[n] = *(const v8bf*)(w1t + (size_t)(jbase + n*16 + l16)*128 + ps*32 + quad*8);
        #pragma unroll
        for (int n=0;n<16;++n)
            acc[n] = __builtin_amdgcn_mfma_f32_16x16x32_bf16(a, bb[n], acc[n], 0, 0, 0);
    }

    float w2v[16];
    #pragma unroll
    for (int n=0;n<16;++n) w2v[n] = w2[jbase + n*16 + l16];

    #pragma unroll
    for (int r=0;r<4;++r){
        float s = 0.f;
        #pragma unroll
        for (int n=0;n<16;++n){
            float v = acc[n][r];
            s += (v / (1.f + expf(-v))) * w2v[n];
        }
        #pragma unroll
        for (int off=8; off>0; off>>=1) s += __shfl_xor(s, off, 16);
        if (l16 == 0) red2[wv][quad*4 + r] = s;
    }
    __syncthreads();
    if (t < 16)
        out[rowbase + t] = red2[0][t] + red2[1][t] + b2[0];
}

// ---------------------------------------------------------------------------
extern "C" void kernel_launch(void* const* d_in, const int* in_sizes, int n_in,
                              void* d_out, int out_size, void* d_ws, size_t ws_size,
                              hipStream_t stream)
{
    const float* x     = (const float*)d_in[0];
    const float* we_g  = (const float*)d_in[1];
    const float* we_b  = (const float*)d_in[2];
    const float* we_w1 = (const float*)d_in[3];
    const float* we_w2 = (const float*)d_in[4];
    const float* we_b2 = (const float*)d_in[5];
    const float* om_g  = (const float*)d_in[6];
    const float* om_b  = (const float*)d_in[7];
    const float* om_w1 = (const float*)d_in[8];
    const float* om_w2 = (const float*)d_in[9];
    const float* om_b2 = (const float*)d_in[10];

    int N  = in_sizes[0] / 64;     // 2048

    char* ws = (char*)d_ws;
    size_t offV = 0;
    size_t szV  = (size_t)65*16*4*128*8*2;       // 8,519,680
    size_t offQ = offV + szV;
    size_t szQ  = (size_t)N*512*2;               // 2 MB
    size_t offH = offQ + szQ;
    size_t szH  = (size_t)65*N*4;
    size_t offP = offH + szH;
    size_t szP  = (size_t)(N/128)*33*16384*2;    // 17.3 MB fp16
    size_t offL = offP + szP;
    size_t szL  = (size_t)N*128*2;
    size_t offW = offL + szL;                    // +128 KB

    unsigned short* Vt2 = (unsigned short*)(ws + offV);
    unsigned short* Q2  = (unsigned short*)(ws + offQ);
    float* Ht           = (float*)(ws + offH);
    unsigned short* Par = (unsigned short*)(ws + offP);
    unsigned short* W1t = (unsigned short*)(ws + offW);
    float* out = (float*)d_out;

    hipLaunchKernelGGL(k_pre,  dim3(264 + N/4), dim3(256), 0, stream,
                       we_w2, we_b2, Vt2, om_w1, W1t, x, we_g, we_b, we_w1, Q2, Ht, N);
    hipLaunchKernelGGL(k_main, dim3(80*8),      dim3(256), 0, stream, Q2, Vt2, Ht, Par, N);
    hipLaunchKernelGGL(k_tail, dim3(N/16),      dim3(128), 0, stream,
                       Par, om_g, om_b, W1t, om_w2, om_b2, out, N);
}

// Round 6
// 126.799 us; speedup vs baseline: 1.1421x; 1.0645x over previous
//
#include <hip/hip_runtime.h>
#include <hip/hip_bf16.h>
#include <cstdint>

#define EPS 1e-5f
#define PATH_COEFF 0.04419417382415922f   // 1/sqrt(512)
#define CG110     0.5773502691896258f     // 1/sqrt(3)

typedef __bf16 v8bf __attribute__((ext_vector_type(8)));
typedef float  v4f  __attribute__((ext_vector_type(4)));
typedef _Float16 v4h __attribute__((ext_vector_type(4)));

static __device__ __forceinline__ unsigned short f2bf(float x){
    unsigned int u = __builtin_bit_cast(unsigned int, x);
    u += 0x7fffu + ((u >> 16) & 1u);      // RNE
    return (unsigned short)(u >> 16);
}
static __device__ __forceinline__ unsigned short f2h(float x){
    return __builtin_bit_cast(unsigned short, (_Float16)x);
}
// async global->LDS, 16B per lane; lds dest = wave-uniform base + lane*16
static __device__ __forceinline__ void gload16(const unsigned short* g, unsigned short* l){
    __builtin_amdgcn_global_load_lds(
        (const __attribute__((address_space(1))) unsigned int*)g,
        (__attribute__((address_space(3))) unsigned int*)l, 16, 0, 0);
}

// ---------------------------------------------------------------------------
// K0: fused prep. blocks [0,260): we_w2/we_b2 -> Vt2 frag-major (8KB LDS);
// [260,264): om_w1 -> w1t bf16 transpose; [264,776): per-row prep, wave/row,
// with LDS-transposed Q2/Ht stores (full 64B sectors).
// ---------------------------------------------------------------------------
__global__ __launch_bounds__(256)
void k_pre(const float* __restrict__ w2, const float* __restrict__ b2,
           unsigned short* __restrict__ Vt2,
           const float* __restrict__ om_w1, unsigned short* __restrict__ w1t,
           const float* __restrict__ x, const float* __restrict__ lng,
           const float* __restrict__ lnb, const float* __restrict__ we_w1,
           unsigned short* __restrict__ Q2, float* __restrict__ Ht, int N)
{
    __shared__ __align__(16) unsigned short tile[32][128];   // 8 KB
    __shared__ __align__(16) uint4 qtile[64][4];             // 4 KB
    __shared__ float htile[4][65];                           // 1.04 KB
    int b = blockIdx.x;
    int t = threadIdx.x;

    if (b < 260){
        // ---- convV: Vt2[k][ps16][quad4][w128][8p] bf16 ----
        int k    = b >> 2;
        int slab = b & 3;
        const float* srcbase = (k < 64) ? (w2 + (size_t)k * 65536) : b2;
        for (int chunk = 0; chunk < 4; ++chunk){
            int pbase = slab*128 + chunk*32;
            #pragma unroll
            for (int i = 0; i < 4; ++i){
                int g = t + 256*i;
                int ploc = g >> 5, c4 = g & 31;
                const float4 v = *(const float4*)(srcbase + (size_t)(pbase + ploc)*128 + c4*4);
                unsigned int w0 = (unsigned)f2bf(v.x) | ((unsigned)f2bf(v.y) << 16);
                unsigned int w1 = (unsigned)f2bf(v.z) | ((unsigned)f2bf(v.w) << 16);
                *(uint2*)&tile[ploc][c4*4] = make_uint2(w0, w1);
            }
            __syncthreads();
            int w = t & 127, h = t >> 7;
            int ps = slab*4 + chunk;
            unsigned int words[8];
            #pragma unroll
            for (int g2 = 0; g2 < 8; ++g2)
                words[g2] = (unsigned)tile[h*16 + g2*2][w] | ((unsigned)tile[h*16 + g2*2 + 1][w] << 16);
            unsigned short* dq0 = Vt2 + (((size_t)(k*16 + ps)*4 + 2*h    )*128 + w)*8;
            unsigned short* dq1 = Vt2 + (((size_t)(k*16 + ps)*4 + 2*h + 1)*128 + w)*8;
            *(uint4*)dq0 = make_uint4(words[0], words[1], words[2], words[3]);
            *(uint4*)dq1 = make_uint4(words[4], words[5], words[6], words[7]);
            __syncthreads();
        }
    } else if (b < 264){
        // ---- convW: w1t[j512][w128] bf16 = om_w1[w][j] ----
        int j0 = (b - 260) * 128;
        for (int chunk = 0; chunk < 4; ++chunk){
            #pragma unroll
            for (int i = 0; i < 4; ++i){
                int g = t + 256*i;
                int wloc = g >> 5, c4 = g & 31;
                int w = chunk*32 + wloc;
                const float4 v = *(const float4*)(om_w1 + (size_t)w*512 + j0 + c4*4);
                unsigned int a = (unsigned)f2bf(v.x) | ((unsigned)f2bf(v.y) << 16);
                unsigned int bb = (unsigned)f2bf(v.z) | ((unsigned)f2bf(v.w) << 16);
                *(uint2*)&tile[wloc][c4*4] = make_uint2(a, bb);
            }
            __syncthreads();
            int jl = t & 127, h = t >> 7;
            unsigned int words[8];
            #pragma unroll
            for (int g2 = 0; g2 < 8; ++g2)
                words[g2] = (unsigned)tile[h*16 + g2*2][jl] | ((unsigned)tile[h*16 + g2*2 + 1][jl] << 16);
            unsigned short* dst = w1t + (size_t)(j0 + jl)*128 + chunk*32 + h*16;
            *(uint4*)dst       = make_uint4(words[0], words[1], words[2], words[3]);
            *(uint4*)(dst + 8) = make_uint4(words[4], words[5], words[6], words[7]);
            __syncthreads();
        }
    } else {
        // ---- prep: wave per row, 4 rows/block; LDS transpose -> dense stores
        int wv = t >> 6, lane = t & 63;
        int row0 = (b - 264)*4;
        int row  = row0 + wv;
        const float* xr = x + (size_t)row * 64;
        float f[16]; float mu = 0.f;
        #pragma unroll
        for (int u = 0; u < 16; ++u){ f[u] = xr[u]; mu += f[u]; }
        mu *= (1.f/16.f);
        float var = 0.f;
        #pragma unroll
        for (int u = 0; u < 16; ++u){ float d = f[u] - mu; var += d*d; }
        var *= (1.f/16.f);
        float inv = rsqrtf(var + EPS);
        float lnf[16];
        #pragma unroll
        for (int u = 0; u < 16; ++u) lnf[u] = (f[u]-mu)*inv*lng[u] + lnb[u];
        float h1 = 0.f;
        #pragma unroll
        for (int u = 0; u < 16; ++u) h1 += lnf[u] * we_w1[u*64 + lane];
        float h = h1 / (1.f + expf(-h1));
        htile[wv][lane] = h;
        if (lane == 0) htile[wv][64] = 1.f;

        union { unsigned short qs[8]; uint4 v; } qu;
        #pragma unroll
        for (int j = 0; j < 8; ++j){
            int p = lane*8 + j;
            float q;
            if (p < 256){
                int u = p >> 4, v = p & 15;
                q = PATH_COEFF * f[u] * f[v];
            } else {
                int pp = p - 256;
                int u = pp >> 4, v = pp & 15;
                const float* ya = xr + 16 + u*3;
                const float* yb = xr + 16 + v*3;
                q = (PATH_COEFF * CG110) * (ya[0]*yb[0] + ya[1]*yb[1] + ya[2]*yb[2]);
            }
            qu.qs[j] = f2bf(q);
        }
        qtile[lane][wv] = qu.v;
        __syncthreads();

        int rb = row0 >> 6, r64base = row0 & 63;
        {
            int slot = t >> 2, rr = t & 3;
            ((uint4*)Q2)[(size_t)rb*4096 + (size_t)slot*64 + r64base + rr] = qtile[slot][rr];
        }
        if (t < 65){
            float4 hv = make_float4(htile[0][t], htile[1][t], htile[2][t], htile[3][t]);
            *(float4*)(Ht + (size_t)t*N + row0) = hv;
        }
    }
}

// ---------------------------------------------------------------------------
// K1 (Kg=2, LDS-staged dbuf): block owns kg pair {2kg,2kg+1}. Per ps, stage
// A(8KB: both rb halves)+B0(8KB)+B1(8KB) into LDS via global_load_lds w16
// (6 insts/block), double-buffered; prefetch ps+1 issued BEFORE compute(ps);
// one __syncthreads per ps. Each byte enters the CU once (L2 traffic halved).
// Epilogue stile aliases the staging buffer (post-barrier). 48KB LDS, lb(256,2).
// ---------------------------------------------------------------------------
__global__ __launch_bounds__(256, 2)
void k_main(const unsigned short* __restrict__ Q2, const unsigned short* __restrict__ Vt2,
            const float* __restrict__ Ht, unsigned short* __restrict__ partial, int N)
{
    __shared__ __align__(16) unsigned short sbuf[2][12288];   // 2 x 24KB
    int g = blockIdx.x & 7;
    int j = blockIdx.x >> 3;
    int kg, mb;
    if (j < 64){ mb = j >> 2; kg = g*4 + (j & 3); }
    else { if (g != 0) return; mb = j - 64; kg = 32; }

    int tid  = threadIdx.x;
    int lane = tid & 63, wv = tid >> 6;
    int r2 = wv >> 1, c2 = wv & 1;
    int quad = lane >> 4, l16 = lane & 15;
    int rowbase = mb*128 + r2*64;
    int rb0 = (mb*128) >> 6;            // first of the two rb halves
    int wbase = c2*64;

    int k0 = kg*2;                       // kg=32 -> k0=64
    int k1 = (kg == 32) ? 64 : k0 + 1;
    float sel = (kg == 32) ? 0.f : 1.f;

    const unsigned short* gA0 = Q2  + (size_t)rb0*32768;
    const unsigned short* gA1 = Q2  + (size_t)(rb0+1)*32768;
    const unsigned short* gB0 = Vt2 + (size_t)k0*65536;
    const unsigned short* gB1 = Vt2 + (size_t)k1*65536;

    // staging: 24 chunks of 1KB; wave wv issues chunks j = wv + 4*c, c=0..5
    // lds shorts: A0 [0,2048) A1 [2048,4096) B0 [4096,8192) B1 [8192,12288)
#define STAGE(BUF, PS)                                                        \
    {                                                                         \
        unsigned short* lb_ = &sbuf[BUF][0];                                  \
        _Pragma("unroll")                                                     \
        for (int c_ = 0; c_ < 6; ++c_){                                       \
            int j_ = wv + c_*4;                                               \
            const unsigned short* gs_;                                        \
            if (j_ < 4)       gs_ = gA0 + (PS)*2048 + j_*512;                 \
            else if (j_ < 8)  gs_ = gA1 + (PS)*2048 + (j_-4)*512;             \
            else if (j_ < 16) gs_ = gB0 + (PS)*4096 + (j_-8)*512;             \
            else              gs_ = gB1 + (PS)*4096 + (j_-16)*512;            \
            gload16(gs_ + lane*8, lb_ + j_*512 + lane*8);                     \
        }                                                                     \
    }

    v4f accA[4][4], accB[4][4];
    #pragma unroll
    for (int m=0;m<4;++m)
      #pragma unroll
      for (int n=0;n<4;++n)
        #pragma unroll
        for (int r=0;r<4;++r){ accA[m][n][r] = 0.f; accB[m][n][r] = 0.f; }

    STAGE(0, 0);
    __syncthreads();

    int abase = r2*2048 + quad*512 + l16*8;
    int bbase = quad*1024 + wbase*8 + l16*8;

    int buf = 0;
    for (int ps = 0; ps < 16; ++ps){
        if (ps < 15) STAGE(buf^1, ps+1);
        const unsigned short* lbuf = &sbuf[buf][0];
        v8bf a[4], b0[4], b1[4];
        #pragma unroll
        for (int m=0;m<4;++m) a[m]  = *(const v8bf*)(lbuf + abase + m*128);
        #pragma unroll
        for (int n=0;n<4;++n) b0[n] = *(const v8bf*)(lbuf + 4096 + bbase + n*128);
        #pragma unroll
        for (int n=0;n<4;++n) b1[n] = *(const v8bf*)(lbuf + 8192 + bbase + n*128);
        #pragma unroll
        for (int m=0;m<4;++m)
          #pragma unroll
          for (int n=0;n<4;++n)
            accA[m][n] = __builtin_amdgcn_mfma_f32_16x16x32_bf16(a[m], b0[n], accA[m][n], 0, 0, 0);
        #pragma unroll
        for (int m=0;m<4;++m)
          #pragma unroll
          for (int n=0;n<4;++n)
            accB[m][n] = __builtin_amdgcn_mfma_f32_16x16x32_bf16(a[m], b1[n], accB[m][n], 0, 0, 0);
        __syncthreads();
        buf ^= 1;
    }
#undef STAGE

    // H-fold both k's; stage fp16 tile in wave-private slice of sbuf (safe:
    // final __syncthreads above drained all staging reads/writes)
    const float* hp0 = Ht + (size_t)k0*N + rowbase + quad*4;
    const float* hp1 = Ht + (size_t)k1*N + rowbase + quad*4;
    unsigned short* my = &sbuf[0][0] + wv*4608;
    #pragma unroll
    for (int m=0;m<4;++m){
        v4f h0 = *(const v4f*)(hp0 + m*16);
        v4f h1 = *(const v4f*)(hp1 + m*16);
        #pragma unroll
        for (int n=0;n<4;++n)
          #pragma unroll
          for (int r=0;r<4;++r)
            my[(m*16 + quad*4 + r)*72 + n*16 + l16] =
                f2h(h0[r]*accA[m][n][r] + sel*h1[r]*accB[m][n][r]);
    }
    // dense stores: 8 insts x (8 rows x 128B), tile-major destination
    unsigned short* gp = partial + ((size_t)(mb*33 + kg))*16384
                                 + (size_t)(r2*64)*128 + wbase;
    #pragma unroll
    for (int i = 0; i < 8; ++i){
        int row = i*8 + (lane >> 3);
        int c16 = (lane & 7)*8;
        uint4 v = *(const uint4*)&my[row*72 + c16];
        *(uint4*)(gp + (size_t)row*128 + c16) = v;
    }
}

// ---------------------------------------------------------------------------
// K2 (fused tail): reduce 33 fp16 slices + LayerNorm -> LDS bf16, then
// out[n] = silu(lnf @ om_w1) @ om_w2 + om_b2. 128 blocks x 256 thr, 16 rows.
// Phase 1: thread owns (row = t>>4, w = (t&15)*8), 16B loads at 32KB stride.
// Phase 2: 4 waves, wave wv owns j-range [wv*128,+128): acc[8] MFMA tiles.
// ---------------------------------------------------------------------------
__global__ __launch_bounds__(256)
void k_tail(const unsigned short* __restrict__ partial, const float* __restrict__ g,
            const float* __restrict__ b, const unsigned short* __restrict__ w1t,
            const float* __restrict__ w2, const float* __restrict__ b2,
            float* __restrict__ out, int N)
{
    __shared__ __align__(16) unsigned short lnf_lds[16][128];   // 4 KB
    __shared__ float red2[4][16];
    int t = threadIdx.x;
    int rowbase = blockIdx.x * 16;
    int mb = rowbase >> 7;
    const unsigned short* pbase = partial + (size_t)mb*33*16384;

    // ---- phase 1: reduce + LN (one (row,w8) pair per thread) ----
    {
        int rl  = t >> 4;                      // 0..15
        int w8  = (t & 15) * 8;
        int rin = (rowbase + rl) & 127;
        const unsigned short* p0 = pbase + (size_t)rin*128 + w8;

        float s[8];
        #pragma unroll
        for (int j2 = 0; j2 < 8; ++j2) s[j2] = 0.f;
        #pragma unroll 11
        for (int sl = 0; sl < 33; ++sl){
            uint4 raw = *(const uint4*)(p0 + (size_t)sl*16384);
            union { uint4 u; _Float16 h[8]; } cv; cv.u = raw;
            #pragma unroll
            for (int j2 = 0; j2 < 8; ++j2) s[j2] += (float)cv.h[j2];
        }
        float sum = 0.f, sq = 0.f;
        #pragma unroll
        for (int j2 = 0; j2 < 8; ++j2){ sum += s[j2]; sq += s[j2]*s[j2]; }
        #pragma unroll
        for (int off = 8; off > 0; off >>= 1){
            sum += __shfl_xor(sum, off, 16);
            sq  += __shfl_xor(sq,  off, 16);
        }
        float mu  = sum * (1.f/128.f);
        float var = sq * (1.f/128.f) - mu*mu;
        float inv = rsqrtf(var + EPS);
        unsigned short o[8];
        #pragma unroll
        for (int j2 = 0; j2 < 8; ++j2)
            o[j2] = f2bf((s[j2]-mu)*inv*g[w8+j2] + b[w8+j2]);
        *(uint4*)&lnf_lds[rl][w8] = *(uint4*)o;
    }
    __syncthreads();

    // ---- phase 2: silu(lnf @ om_w1) @ om_w2 ----
    int lane = t & 63, wv = t >> 6;
    int quad = lane >> 4, l16 = lane & 15;
    int jbase = wv * 128;

    v4f acc[8];
    #pragma unroll
    for (int n=0;n<8;++n)
      #pragma unroll
      for (int r=0;r<4;++r) acc[n][r] = 0.f;

    #pragma unroll
    for (int ps = 0; ps < 4; ++ps){
        v8bf a = *(const v8bf*)&lnf_lds[l16][ps*32 + quad*8];
        v8bf bb[8];
        #pragma unroll
        for (int n=0;n<8;++n)
            bb[n] = *(const v8bf*)(w1t + (size_t)(jbase + n*16 + l16)*128 + ps*32 + quad*8);
        #pragma unroll
        for (int n=0;n<8;++n)
            acc[n] = __builtin_amdgcn_mfma_f32_16x16x32_bf16(a, bb[n], acc[n], 0, 0, 0);
    }

    float w2v[8];
    #pragma unroll
    for (int n=0;n<8;++n) w2v[n] = w2[jbase + n*16 + l16];

    #pragma unroll
    for (int r=0;r<4;++r){
        float s = 0.f;
        #pragma unroll
        for (int n=0;n<8;++n){
            float v = acc[n][r];
            s += (v / (1.f + expf(-v))) * w2v[n];
        }
        #pragma unroll
        for (int off=8; off>0; off>>=1) s += __shfl_xor(s, off, 16);
        if (l16 == 0) red2[wv][quad*4 + r] = s;
    }
    __syncthreads();
    if (t < 16)
        out[rowbase + t] = red2[0][t] + red2[1][t] + red2[2][t] + red2[3][t] + b2[0];
}

// ---------------------------------------------------------------------------
extern "C" void kernel_launch(void* const* d_in, const int* in_sizes, int n_in,
                              void* d_out, int out_size, void* d_ws, size_t ws_size,
                              hipStream_t stream)
{
    const float* x     = (const float*)d_in[0];
    const float* we_g  = (const float*)d_in[1];
    const float* we_b  = (const float*)d_in[2];
    const float* we_w1 = (const float*)d_in[3];
    const float* we_w2 = (const float*)d_in[4];
    const float* we_b2 = (const float*)d_in[5];
    const float* om_g  = (const float*)d_in[6];
    const float* om_b  = (const float*)d_in[7];
    const float* om_w1 = (const float*)d_in[8];
    const float* om_w2 = (const float*)d_in[9];
    const float* om_b2 = (const float*)d_in[10];

    int N  = in_sizes[0] / 64;     // 2048

    char* ws = (char*)d_ws;
    size_t offV = 0;
    size_t szV  = (size_t)65*16*4*128*8*2;       // 8,519,680
    size_t offQ = offV + szV;
    size_t szQ  = (size_t)N*512*2;               // 2 MB
    size_t offH = offQ + szQ;
    size_t szH  = (size_t)65*N*4;
    size_t offP = offH + szH;
    size_t szP  = (size_t)(N/128)*33*16384*2;    // 17.3 MB fp16
    size_t offL = offP + szP;
    size_t szL  = (size_t)N*128*2;
    size_t offW = offL + szL;                    // +128 KB

    unsigned short* Vt2 = (unsigned short*)(ws + offV);
    unsigned short* Q2  = (unsigned short*)(ws + offQ);
    float* Ht           = (float*)(ws + offH);
    unsigned short* Par = (unsigned short*)(ws + offP);
    unsigned short* W1t = (unsigned short*)(ws + offW);
    float* out = (float*)d_out;

    hipLaunchKernelGGL(k_pre,  dim3(264 + N/4), dim3(256), 0, stream,
                       we_w2, we_b2, Vt2, om_w1, W1t, x, we_g, we_b, we_w1, Q2, Ht, N);
    hipLaunchKernelGGL(k_main, dim3(80*8),      dim3(256), 0, stream, Q2, Vt2, Ht, Par, N);
    hipLaunchKernelGGL(k_tail, dim3(N/16),      dim3(256), 0, stream,
                       Par, om_g, om_b, W1t, om_w2, om_b2, out, N);
}